// Round 1
// baseline (126.398 us; speedup 1.0000x reference)
//
#include <hip/hip_runtime.h>
#include <hip/hip_bf16.h>

#define M_DIM 8192
#define K_DIM 4096
#define N_DIM 4096
#define BKb   64
#define BNb   64
#define NCb   64
#define OCCb  4
#define BM    128

typedef __bf16 bf16x8 __attribute__((ext_vector_type(8)));
typedef float  f32x4  __attribute__((ext_vector_type(4)));

__device__ __forceinline__ unsigned short f2bf(float f) {
    unsigned u = __builtin_bit_cast(unsigned, f);
    u += 0x7fffu + ((u >> 16) & 1u);          // round-to-nearest-even
    return (unsigned short)(u >> 16);
}

__global__ __launch_bounds__(256) void sparse_linear_kernel(
    const float* __restrict__ A, const float* __restrict__ Bd,
    const int* __restrict__ rowi, const int* __restrict__ di,
    float* __restrict__ C)
{
    // LDS: A tile [128][64] bf16 (swizzled), B tile transposed [n=64][k=64] bf16 (swizzled)
    __shared__ __align__(16) unsigned short Al[BM * BKb];
    __shared__ __align__(16) unsigned short Bl[BNb * BKb];
    char* Ab = (char*)Al;
    char* Bb = (char*)Bl;

    const int t   = threadIdx.x;
    const int bid = blockIdx.x;
    // decode so the 4 column blocks sharing the same A panel are consecutive:
    // j = bid&3, rest = bid>>2, mtile = rest&63, tg = rest>>6, c = tg + 16*j
    const int j     = bid & 3;
    const int rest  = bid >> 2;
    const int mtile = rest & 63;
    const int tg    = rest >> 6;
    const int c     = tg + 16 * j;
    const int m0    = mtile * BM;

    const int lane = t & 63;
    const int w    = t >> 6;
    const int wr   = w >> 1, wc = w & 1;   // 2x2 waves, wave tile 64x32

    f32x4 acc[4][2];
    #pragma unroll
    for (int m = 0; m < 4; ++m)
        #pragma unroll
        for (int n = 0; n < 2; ++n)
            acc[m][n] = f32x4{0.f, 0.f, 0.f, 0.f};

    for (int s = 0; s < OCCb; ++s) {
        const int r = rowi[s * NCb + c];
        const int d = di[s * NCb + c];

        // ---- issue global loads (fp32) into registers ----
        float4 av[8];
        const float* Ag = A + (long)m0 * K_DIM + r * BKb;
        #pragma unroll
        for (int i = 0; i < 8; ++i) {
            int flat4 = i * 256 + t;
            int row   = flat4 >> 4;        // 16 float4 per row
            int k4    = flat4 & 15;
            av[i] = *(const float4*)(Ag + (long)row * K_DIM + k4 * 4);
        }
        float bv[16];
        const float* Bg = Bd + d * BNb;
        #pragma unroll
        for (int i = 0; i < 16; ++i) {
            int flat = i * 256 + t;
            int kk   = flat >> 6;
            int n    = flat & 63;
            bv[i] = Bg[(long)kk * (BNb * 256) + n];   // row stride = BN*TB = 16384
        }

        __syncthreads();   // prior iteration's LDS reads complete

        // ---- convert + LDS write (swizzled) ----
        #pragma unroll
        for (int i = 0; i < 8; ++i) {
            int flat4 = i * 256 + t;
            int row   = flat4 >> 4;
            int k4    = flat4 & 15;
            ushort4 p;
            p.x = f2bf(av[i].x); p.y = f2bf(av[i].y);
            p.z = f2bf(av[i].z); p.w = f2bf(av[i].w);
            *(ushort4*)(Ab + row * 128 + ((k4 * 8) ^ ((row & 7) << 4))) = p;
        }
        #pragma unroll
        for (int i = 0; i < 16; ++i) {
            int flat = i * 256 + t;
            int kk   = flat >> 6;
            int n    = flat & 63;
            *(unsigned short*)(Bb + n * 128 + ((kk * 2) ^ ((n & 7) << 4))) = f2bf(bv[i]);
        }

        __syncthreads();   // tile ready

        // ---- MFMA: K=64 as two K=32 halves ----
        #pragma unroll
        for (int kb = 0; kb < 2; ++kb) {
            const int kbyte = (kb * 32 + (lane >> 4) * 8) * 2;
            bf16x8 af[4], bfv[2];
            #pragma unroll
            for (int m = 0; m < 4; ++m) {
                int row = wr * 64 + m * 16 + (lane & 15);
                af[m] = *(bf16x8*)(Ab + row * 128 + (kbyte ^ ((row & 7) << 4)));
            }
            #pragma unroll
            for (int n = 0; n < 2; ++n) {
                int rb = wc * 32 + n * 16 + (lane & 15);
                bfv[n] = *(bf16x8*)(Bb + rb * 128 + (kbyte ^ ((rb & 7) << 4)));
            }
            #pragma unroll
            for (int m = 0; m < 4; ++m)
                #pragma unroll
                for (int n = 0; n < 2; ++n)
                    acc[m][n] = __builtin_amdgcn_mfma_f32_16x16x32_bf16(
                        af[m], bfv[n], acc[m][n], 0, 0, 0);
        }
    }

    // ---- epilogue: C/D layout col=lane&15, row=(lane>>4)*4+v ----
    #pragma unroll
    for (int m = 0; m < 4; ++m)
        #pragma unroll
        for (int n = 0; n < 2; ++n)
            #pragma unroll
            for (int v = 0; v < 4; ++v) {
                int row = wr * 64 + m * 16 + (lane >> 4) * 4 + v;
                int col = wc * 32 + n * 16 + (lane & 15);
                C[(long)(m0 + row) * N_DIM + c * BNb + col] = acc[m][n][v];
            }
}

extern "C" void kernel_launch(void* const* d_in, const int* in_sizes, int n_in,
                              void* d_out, int out_size, void* d_ws, size_t ws_size,
                              hipStream_t stream) {
    const float* A    = (const float*)d_in[0];
    const float* Bd   = (const float*)d_in[1];
    const int*   rowi = (const int*)d_in[2];
    const int*   di   = (const int*)d_in[3];
    float*       C    = (float*)d_out;

    dim3 grid(64 * 64);   // (M/BM=64) x (NC=64), decoded in-kernel
    dim3 block(256);
    hipLaunchKernelGGL(sparse_linear_kernel, grid, block, 0, stream,
                       A, Bd, rowi, di, C);
}